// Round 4
// baseline (88.323 us; speedup 1.0000x reference)
//
#include <hip/hip_runtime.h>
#include <math.h>

#define BATCH 8
#define NTOK  4096
#define DIM   64
#define BM    128
#define NT    (NTOK / BM)            // 32 tiles per dim
#define TPB   (NT * (NT + 1) / 2)    // 528 upper-tri tile pairs per batch
#define KAPPA 0.5f
#define FIXM  60.0f   // fixed lse shift: max logit = kappa*max||e||^2 ~ 55 < 60

typedef _Float16 f16x8  __attribute__((ext_vector_type(8)));
typedef __fp16   h2     __attribute__((ext_vector_type(2)));  // cvt_pkrtz return type
typedef float    f32x16 __attribute__((ext_vector_type(16)));

__device__ __forceinline__ f16x8 pack8(float4 lo, float4 hi) {
    union { f16x8 v; h2 p[4]; } u;
    u.p[0] = __builtin_amdgcn_cvt_pkrtz(lo.x, lo.y);
    u.p[1] = __builtin_amdgcn_cvt_pkrtz(lo.z, lo.w);
    u.p[2] = __builtin_amdgcn_cvt_pkrtz(hi.x, hi.y);
    u.p[3] = __builtin_amdgcn_cvt_pkrtz(hi.z, hi.w);
    return u.v;
}

// One block per (batch, upper-tri 128x128 tile pair). Gram tile via
// mfma_f32_32x32x16_f16. Fixed-M epilogue: each wave independently
// shuffle-sums exp(kappa*v - FIXM) over its 64x64 subtile and writes one
// float — no post-MFMA barriers. Whole-tile weighting (diag=1, offdiag=2)
// keeps the epilogue permutation-invariant w.r.t. the MFMA fragment map.
__global__ __launch_bounds__(256, 4)
void gram_lse_partial(const float* __restrict__ emb, float* __restrict__ ws) {
    // Panels as 16-B units: unit (g, row) at [g*128 + (row^g)], g=k/8 in 0..7.
    __shared__ f16x8 As[8 * BM];   // 16 KB
    __shared__ f16x8 Bs[8 * BM];   // 16 KB

    const int tid = threadIdx.x;
    const int bb  = blockIdx.x;
    const int b   = bb / TPB;
    int t = bb - b * TPB;
    int ti = 0;
    while (t >= NT - ti) { t -= NT - ti; ++ti; }
    const int tj = ti + t;
    const bool diag = (ti == tj);

    const float* embA = emb + ((size_t)b * NTOK + (size_t)ti * BM) * DIM;
    const float* embB = emb + ((size_t)b * NTOK + (size_t)tj * BM) * DIM;

    // ---- global fp32 -> LDS f16 staging (packed converts) ----
    {
        const int g  = tid & 7;     // k-group: k = 8g..8g+7
        const int r0 = tid >> 3;    // 0..31
#pragma unroll
        for (int p = 0; p < 4; ++p) {
            const int row = r0 + 32 * p;
            const int su  = g * BM + (row ^ g);
            const float4 a0 = *(const float4*)(embA + (size_t)row * DIM + g * 8);
            const float4 a1 = *(const float4*)(embA + (size_t)row * DIM + g * 8 + 4);
            As[su] = pack8(a0, a1);
            if (!diag) {
                const float4 b0 = *(const float4*)(embB + (size_t)row * DIM + g * 8);
                const float4 b1 = *(const float4*)(embB + (size_t)row * DIM + g * 8 + 4);
                Bs[su] = pack8(b0, b1);
            }
        }
    }
    __syncthreads();

    // ---- MFMA: each wave computes a 64x64 subtile (2x2 of 32x32, K=64) ----
    const int lane = tid & 63;
    const int w    = tid >> 6;
    const int half = lane >> 5;    // k-half within fragment
    const int ln31 = lane & 31;
    const int waveR = (w & 1) * 64;
    const int waveC = (w >> 1) * 64;
    const f16x8* __restrict__ Bp = diag ? As : Bs;

    f32x16 acc00 = {}, acc01 = {}, acc10 = {}, acc11 = {};
#pragma unroll
    for (int s = 0; s < 4; ++s) {
        const int g = 2 * s + half;
        const f16x8 a0 = As[g * BM + ((waveR + ln31) ^ g)];
        const f16x8 a1 = As[g * BM + ((waveR + 32 + ln31) ^ g)];
        const f16x8 b0 = Bp[g * BM + ((waveC + ln31) ^ g)];
        const f16x8 b1 = Bp[g * BM + ((waveC + 32 + ln31) ^ g)];
        acc00 = __builtin_amdgcn_mfma_f32_32x32x16_f16(a0, b0, acc00, 0, 0, 0);
        acc01 = __builtin_amdgcn_mfma_f32_32x32x16_f16(a0, b1, acc01, 0, 0, 0);
        acc10 = __builtin_amdgcn_mfma_f32_32x32x16_f16(a1, b0, acc10, 0, 0, 0);
        acc11 = __builtin_amdgcn_mfma_f32_32x32x16_f16(a1, b1, acc11, 0, 0, 0);
    }

    // ---- epilogue: per-wave sum of exp(kappa*v - FIXM), no barriers ----
    float lsum = 0.f;
#pragma unroll
    for (int e = 0; e < 16; ++e) {
        lsum += __expf(fmaf(KAPPA, acc00[e], -FIXM));
        lsum += __expf(fmaf(KAPPA, acc01[e], -FIXM));
        lsum += __expf(fmaf(KAPPA, acc10[e], -FIXM));
        lsum += __expf(fmaf(KAPPA, acc11[e], -FIXM));
    }
#pragma unroll
    for (int off = 32; off > 0; off >>= 1)
        lsum += __shfl_xor(lsum, off);
    if (lane == 0)
        ws[4 * (size_t)bb + w] = (diag ? 1.f : 2.f) * lsum;
}

// 1 block, 8 waves: wave w sums batch w's 528*4 partial sums; fixed-M lse.
__global__ __launch_bounds__(512)
void reduce_lse(const float* __restrict__ ws, float* __restrict__ out) {
    const int tid  = threadIdx.x;
    const int w    = tid >> 6;
    const int lane = tid & 63;
    __shared__ float lse[BATCH];

    const float* p = ws + (size_t)w * TPB * 4;
    float s = 0.f;
    for (int idx = lane; idx < TPB * 4; idx += 64) s += p[idx];
#pragma unroll
    for (int off = 32; off > 0; off >>= 1) s += __shfl_xor(s, off);

    if (lane == 0) lse[w] = FIXM + logf(s);
    __syncthreads();
    if (tid == 0) {
        float a = 0.f;
        for (int i = 0; i < BATCH; ++i) a += lse[i];
        out[0] = a * (1.f / BATCH);
    }
}

extern "C" void kernel_launch(void* const* d_in, const int* in_sizes, int n_in,
                              void* d_out, int out_size, void* d_ws, size_t ws_size,
                              hipStream_t stream) {
    const float* emb = (const float*)d_in[0];
    float* out = (float*)d_out;
    float* ws  = (float*)d_ws;   // BATCH*TPB*4 floats = 67,584 B

    gram_lse_partial<<<BATCH * TPB, 256, 0, stream>>>(emb, ws);
    reduce_lse<<<1, 512, 0, stream>>>(ws, out);
}

// Round 5
// 86.578 us; speedup vs baseline: 1.0202x; 1.0202x over previous
//
#include <hip/hip_runtime.h>
#include <math.h>

#define BATCH 8
#define NTOK  4096
#define DIM   64
#define BM    128
#define NT    (NTOK / BM)            // 32 tiles per dim
#define TPB   (NT * (NT + 1) / 2)    // 528 upper-tri tile pairs per batch
#define KAPPA 0.5f
#define FIXM  60.0f   // fixed lse shift: max logit = kappa*max||e||^2 ~ 55 < 60
#define LOG2E 1.4426950408889634f
#define C1    (KAPPA * LOG2E)        // exp(kv - M) = exp2(C1*v + C2)
#define C2    (-FIXM * LOG2E)

typedef _Float16 f16x8  __attribute__((ext_vector_type(8)));
typedef __fp16   h2     __attribute__((ext_vector_type(2)));  // cvt_pkrtz return type
typedef float    f32x16 __attribute__((ext_vector_type(16)));

__device__ __forceinline__ float exp2_fast(float x) {
#if __has_builtin(__builtin_amdgcn_exp2f)
    return __builtin_amdgcn_exp2f(x);   // bare v_exp_f32
#else
    return __expf(x * 0.6931471805599453f);
#endif
}

__device__ __forceinline__ f16x8 pack8(float4 lo, float4 hi) {
    union { f16x8 v; h2 p[4]; } u;
    u.p[0] = __builtin_amdgcn_cvt_pkrtz(lo.x, lo.y);
    u.p[1] = __builtin_amdgcn_cvt_pkrtz(lo.z, lo.w);
    u.p[2] = __builtin_amdgcn_cvt_pkrtz(hi.x, hi.y);
    u.p[3] = __builtin_amdgcn_cvt_pkrtz(hi.z, hi.w);
    return u.v;
}

// One block per (batch, upper-tri 128x128 tile pair). Gram tile via
// mfma_f32_32x32x16_f16. Fixed-M epilogue: each wave independently
// shuffle-sums exp2(C1*v + C2) over its 64x64 subtile, no post-MFMA barriers.
// Whole-tile weighting (diag=1, offdiag=2) keeps the epilogue
// permutation-invariant w.r.t. the MFMA fragment map.
// launch_bounds(256,3): 170-VGPR budget — kernel needs ~130, so no scratch
// spill (the (256,4)=128-reg cap in R4 spilled and cost ~6 us), 3 blocks/CU.
__global__ __launch_bounds__(256, 3)
void gram_lse_partial(const float* __restrict__ emb, float* __restrict__ ws) {
    // Panels as 16-B units: unit (g, row) at [g*128 + (row^g)], g=k/8 in 0..7.
    __shared__ f16x8 As[8 * BM];   // 16 KB
    __shared__ f16x8 Bs[8 * BM];   // 16 KB

    const int tid = threadIdx.x;
    const int bb  = blockIdx.x;
    const int b   = bb / TPB;
    int t = bb - b * TPB;
    int ti = 0;
    while (t >= NT - ti) { t -= NT - ti; ++ti; }
    const int tj = ti + t;
    const bool diag = (ti == tj);

    const float* embA = emb + ((size_t)b * NTOK + (size_t)ti * BM) * DIM;
    const float* embB = emb + ((size_t)b * NTOK + (size_t)tj * BM) * DIM;

    // ---- global fp32 -> LDS f16 staging (packed converts) ----
    {
        const int g  = tid & 7;     // k-group: k = 8g..8g+7
        const int r0 = tid >> 3;    // 0..31
#pragma unroll
        for (int p = 0; p < 4; ++p) {
            const int row = r0 + 32 * p;
            const int su  = g * BM + (row ^ g);
            const float4 a0 = *(const float4*)(embA + (size_t)row * DIM + g * 8);
            const float4 a1 = *(const float4*)(embA + (size_t)row * DIM + g * 8 + 4);
            As[su] = pack8(a0, a1);
            if (!diag) {
                const float4 b0 = *(const float4*)(embB + (size_t)row * DIM + g * 8);
                const float4 b1 = *(const float4*)(embB + (size_t)row * DIM + g * 8 + 4);
                Bs[su] = pack8(b0, b1);
            }
        }
    }
    __syncthreads();

    // ---- MFMA: each wave computes a 64x64 subtile (2x2 of 32x32, K=64) ----
    const int lane = tid & 63;
    const int w    = tid >> 6;
    const int half = lane >> 5;    // k-half within fragment
    const int ln31 = lane & 31;
    const int waveR = (w & 1) * 64;
    const int waveC = (w >> 1) * 64;
    const f16x8* __restrict__ Bp = diag ? As : Bs;

    f32x16 acc00 = {}, acc01 = {}, acc10 = {}, acc11 = {};
#pragma unroll
    for (int s = 0; s < 4; ++s) {
        const int g = 2 * s + half;
        const f16x8 a0 = As[g * BM + ((waveR + ln31) ^ g)];
        const f16x8 a1 = As[g * BM + ((waveR + 32 + ln31) ^ g)];
        const f16x8 b0 = Bp[g * BM + ((waveC + ln31) ^ g)];
        const f16x8 b1 = Bp[g * BM + ((waveC + 32 + ln31) ^ g)];
        acc00 = __builtin_amdgcn_mfma_f32_32x32x16_f16(a0, b0, acc00, 0, 0, 0);
        acc01 = __builtin_amdgcn_mfma_f32_32x32x16_f16(a0, b1, acc01, 0, 0, 0);
        acc10 = __builtin_amdgcn_mfma_f32_32x32x16_f16(a1, b0, acc10, 0, 0, 0);
        acc11 = __builtin_amdgcn_mfma_f32_32x32x16_f16(a1, b1, acc11, 0, 0, 0);
    }

    // ---- epilogue: per-wave sum of exp2(C1*v + C2), no barriers ----
    float lsum = 0.f;
#pragma unroll
    for (int e = 0; e < 16; ++e) {
        lsum += exp2_fast(fmaf(C1, acc00[e], C2));
        lsum += exp2_fast(fmaf(C1, acc01[e], C2));
        lsum += exp2_fast(fmaf(C1, acc10[e], C2));
        lsum += exp2_fast(fmaf(C1, acc11[e], C2));
    }
#pragma unroll
    for (int off = 32; off > 0; off >>= 1)
        lsum += __shfl_xor(lsum, off);
    if (lane == 0)
        ws[4 * (size_t)bb + w] = (diag ? 1.f : 2.f) * lsum;
}

// 1 block, 8 waves: wave w sums batch w's 528*4 partial sums; fixed-M lse.
__global__ __launch_bounds__(512)
void reduce_lse(const float* __restrict__ ws, float* __restrict__ out) {
    const int tid  = threadIdx.x;
    const int w    = tid >> 6;
    const int lane = tid & 63;
    __shared__ float lse[BATCH];

    const float* p = ws + (size_t)w * TPB * 4;
    float s = 0.f;
    for (int idx = lane; idx < TPB * 4; idx += 64) s += p[idx];
#pragma unroll
    for (int off = 32; off > 0; off >>= 1) s += __shfl_xor(s, off);

    if (lane == 0) lse[w] = FIXM + logf(s);
    __syncthreads();
    if (tid == 0) {
        float a = 0.f;
        for (int i = 0; i < BATCH; ++i) a += lse[i];
        out[0] = a * (1.f / BATCH);
    }
}

extern "C" void kernel_launch(void* const* d_in, const int* in_sizes, int n_in,
                              void* d_out, int out_size, void* d_ws, size_t ws_size,
                              hipStream_t stream) {
    const float* emb = (const float*)d_in[0];
    float* out = (float*)d_out;
    float* ws  = (float*)d_ws;   // BATCH*TPB*4 floats = 67,584 B

    gram_lse_partial<<<BATCH * TPB, 256, 0, stream>>>(emb, ws);
    reduce_lse<<<1, 512, 0, stream>>>(ws, out);
}

// Round 6
// 85.648 us; speedup vs baseline: 1.0312x; 1.0109x over previous
//
#include <hip/hip_runtime.h>
#include <math.h>

#define BATCH 8
#define NTOK  4096
#define DIM   64
#define BM    256                    // tile size (256x256 per block)
#define NT    (NTOK / BM)            // 16 tiles per dim
#define TPB   (NT * (NT + 1) / 2)    // 136 upper-tri tile pairs per batch
#define KAPPA 0.5f
#define FIXM  60.0f   // fixed lse shift: max logit = kappa*max||e||^2 ~ 55 < 60
#define LOG2E 1.4426950408889634f
#define C1    (KAPPA * LOG2E)        // exp(kv - M) = exp2(C1*v + C2)
#define C2    (-FIXM * LOG2E)

typedef _Float16 f16x8  __attribute__((ext_vector_type(8)));
typedef __fp16   h2     __attribute__((ext_vector_type(2)));  // cvt_pkrtz return type
typedef float    f32x16 __attribute__((ext_vector_type(16)));

__device__ __forceinline__ float exp2_fast(float x) {
#if __has_builtin(__builtin_amdgcn_exp2f)
    return __builtin_amdgcn_exp2f(x);   // bare v_exp_f32
#else
    return __expf(x * 0.6931471805599453f);
#endif
}

__device__ __forceinline__ f16x8 pack8(float4 lo, float4 hi) {
    union { f16x8 v; h2 p[4]; } u;
    u.p[0] = __builtin_amdgcn_cvt_pkrtz(lo.x, lo.y);
    u.p[1] = __builtin_amdgcn_cvt_pkrtz(lo.z, lo.w);
    u.p[2] = __builtin_amdgcn_cvt_pkrtz(hi.x, hi.y);
    u.p[3] = __builtin_amdgcn_cvt_pkrtz(hi.z, hi.w);
    return u.v;
}

// One block per (batch, upper-tri 256x256 tile pair). 512 threads / 8 waves;
// wave w computes a 128x64 subtile (4x2 grid of 32x32 MFMA tiles, K=64).
// Bigger tile halves Infinity-Cache panel traffic vs 128-tiles (270->139 MB).
// Fixed-M epilogue: per-wave shuffle-sum of exp2(C1*v + C2), no post-MFMA
// barriers. Whole-tile weighting (diag=1, offdiag=2) keeps the epilogue
// permutation-invariant w.r.t. the MFMA fragment map.
__global__ __launch_bounds__(512, 2)
void gram_lse_partial(const float* __restrict__ emb, float* __restrict__ ws) {
    // Panels as 16-B units: unit (g, row) at [g*BM + (row^g)], g=k/8 in 0..7.
    __shared__ f16x8 As[8 * BM];   // 32 KB
    __shared__ f16x8 Bs[8 * BM];   // 32 KB

    const int tid = threadIdx.x;
    const int bb  = blockIdx.x;
    const int b   = bb / TPB;
    int t = bb - b * TPB;
    int ti = 0;
    while (t >= NT - ti) { t -= NT - ti; ++ti; }
    const int tj = ti + t;
    const bool diag = (ti == tj);

    const float* embA = emb + ((size_t)b * NTOK + (size_t)ti * BM) * DIM;
    const float* embB = emb + ((size_t)b * NTOK + (size_t)tj * BM) * DIM;

    // ---- global fp32 -> LDS f16 staging (packed converts) ----
    {
        const int g  = tid & 7;     // k-group: k = 8g..8g+7
        const int r0 = tid >> 3;    // 0..63
#pragma unroll
        for (int p = 0; p < 4; ++p) {
            const int row = r0 + 64 * p;
            const int su  = g * BM + (row ^ g);
            const float4 a0 = *(const float4*)(embA + (size_t)row * DIM + g * 8);
            const float4 a1 = *(const float4*)(embA + (size_t)row * DIM + g * 8 + 4);
            As[su] = pack8(a0, a1);
            if (!diag) {
                const float4 b0 = *(const float4*)(embB + (size_t)row * DIM + g * 8);
                const float4 b1 = *(const float4*)(embB + (size_t)row * DIM + g * 8 + 4);
                Bs[su] = pack8(b0, b1);
            }
        }
    }
    __syncthreads();

    // ---- MFMA: wave w -> rows [128*(w&1), +128) x cols [64*(w>>1), +64) ----
    const int lane  = tid & 63;
    const int w     = tid >> 6;
    const int half  = lane >> 5;   // k-half within fragment
    const int ln31  = lane & 31;
    const int rbase = (w & 1) * 128;
    const int cbase = (w >> 1) * 64;
    const f16x8* __restrict__ Bp = diag ? As : Bs;

    f32x16 acc[4][2] = {};
#pragma unroll
    for (int s = 0; s < 4; ++s) {
        const int g = 2 * s + half;
        f16x8 af[4], bf[2];
#pragma unroll
        for (int i = 0; i < 4; ++i)
            af[i] = As[g * BM + ((rbase + 32 * i + ln31) ^ g)];
#pragma unroll
        for (int j = 0; j < 2; ++j)
            bf[j] = Bp[g * BM + ((cbase + 32 * j + ln31) ^ g)];
#pragma unroll
        for (int i = 0; i < 4; ++i)
#pragma unroll
            for (int j = 0; j < 2; ++j)
                acc[i][j] = __builtin_amdgcn_mfma_f32_32x32x16_f16(
                    af[i], bf[j], acc[i][j], 0, 0, 0);
    }

    // ---- epilogue: per-wave sum of exp2(C1*v + C2), no barriers ----
    float lsum = 0.f;
#pragma unroll
    for (int i = 0; i < 4; ++i)
#pragma unroll
        for (int j = 0; j < 2; ++j)
#pragma unroll
            for (int e = 0; e < 16; ++e)
                lsum += exp2_fast(fmaf(C1, acc[i][j][e], C2));
#pragma unroll
    for (int off = 32; off > 0; off >>= 1)
        lsum += __shfl_xor(lsum, off);
    if (lane == 0)
        ws[8 * (size_t)bb + w] = (diag ? 1.f : 2.f) * lsum;
}

// 1 block, 8 waves: wave w sums batch w's TPB*8 partial sums; fixed-M lse.
__global__ __launch_bounds__(512)
void reduce_lse(const float* __restrict__ ws, float* __restrict__ out) {
    const int tid  = threadIdx.x;
    const int w    = tid >> 6;
    const int lane = tid & 63;
    __shared__ float lse[BATCH];

    const float* p = ws + (size_t)w * TPB * 8;
    float s = 0.f;
    for (int idx = lane; idx < TPB * 8; idx += 64) s += p[idx];
#pragma unroll
    for (int off = 32; off > 0; off >>= 1) s += __shfl_xor(s, off);

    if (lane == 0) lse[w] = FIXM + logf(s);
    __syncthreads();
    if (tid == 0) {
        float a = 0.f;
        for (int i = 0; i < BATCH; ++i) a += lse[i];
        out[0] = a * (1.f / BATCH);
    }
}

extern "C" void kernel_launch(void* const* d_in, const int* in_sizes, int n_in,
                              void* d_out, int out_size, void* d_ws, size_t ws_size,
                              hipStream_t stream) {
    const float* emb = (const float*)d_in[0];
    float* out = (float*)d_out;
    float* ws  = (float*)d_ws;   // BATCH*TPB*8 floats = 34,816 B

    gram_lse_partial<<<BATCH * TPB, 512, 0, stream>>>(emb, ws);
    reduce_lse<<<1, 512, 0, stream>>>(ws, out);
}